// Round 2
// 1972.749 us; speedup vs baseline: 1.1066x; 1.1066x over previous
//
#include <hip/hip_runtime.h>
#include <stdint.h>

#define NN 100000
#define NED 1600000
#define DD 128
#define NE 8
#define ND ((size_t)NN * (size_t)DD)     // elems per expert-plane
#define NDE (ND * NE)                    // elems in interleaved [node][e][f]
#define BNEPS 1e-5f

typedef __attribute__((ext_vector_type(8))) short short8;
typedef __attribute__((ext_vector_type(4))) float float4v;
typedef __attribute__((ext_vector_type(4))) unsigned int uint4v;

__device__ __forceinline__ float bf2f(uint32_t h) {
    union { uint32_t u; float f; } c; c.u = h << 16; return c.f;
}
__device__ __forceinline__ uint16_t f2bf(float x) {
    union { float f; uint32_t u; } c; c.f = x;
    uint32_t r = (c.u + 0x7fffu + ((c.u >> 16) & 1u)) >> 16;
    return (uint16_t)r;
}

// ---------------- degree histogram ----------------
__global__ __launch_bounds__(256) void k_deg(const int* __restrict__ dst, int* __restrict__ deg) {
    int i = blockIdx.x * 256 + threadIdx.x;
    int stride = gridDim.x * 256;
    for (; i < NED; i += stride) atomicAdd(&deg[dst[i]], 1);
}

// ---------------- exclusive scan (3 kernels) ----------------
__global__ __launch_bounds__(1024) void k_scan1(const int* __restrict__ deg, int* __restrict__ rp,
                                                int* __restrict__ bsum) {
    __shared__ int sh[1024];
    int t = threadIdx.x;
    int i = blockIdx.x * 1024 + t;
    int v = (i < NN) ? deg[i] : 0;
    sh[t] = v; __syncthreads();
    for (int off = 1; off < 1024; off <<= 1) {
        int add = (t >= off) ? sh[t - off] : 0;
        __syncthreads();
        sh[t] += add;
        __syncthreads();
    }
    if (i < NN) rp[i] = sh[t] - v;            // exclusive
    if (t == 1023) bsum[blockIdx.x] = sh[1023];
}

__global__ void k_scan2(int* bsum) {
    if (threadIdx.x == 0) {
        int acc = 0;
        for (int j = 0; j < 98; ++j) { int t = bsum[j]; bsum[j] = acc; acc += t; }
    }
}

__global__ __launch_bounds__(1024) void k_scan3(const int* __restrict__ deg, int* __restrict__ rp,
                                                const int* __restrict__ bsum, int* __restrict__ cur,
                                                float* __restrict__ invd) {
    int i = blockIdx.x * 1024 + threadIdx.x;
    if (i == 0) rp[NN] = NED;
    if (i < NN) {
        int r = rp[i] + bsum[blockIdx.x];
        rp[i] = r; cur[i] = r;
        invd[i] = 1.0f / fmaxf((float)deg[i], 1.0f);
    }
}

// ---------------- scatter edges into CSR (sorted by dst) ----------------
__global__ __launch_bounds__(256) void k_scatter(const int* __restrict__ src, const int* __restrict__ dst,
                                                 int* __restrict__ cur, int* __restrict__ esrc) {
    int i = blockIdx.x * 256 + threadIdx.x;
    int stride = gridDim.x * 256;
    for (; i < NED; i += stride) {
        int d = dst[i];
        int p = atomicAdd(&cur[d], 1);
        esrc[p] = src[i];
    }
}

// ---------------- cast x (f32 -> bf16) ----------------
__global__ __launch_bounds__(256) void k_castx(const float* __restrict__ x, uint16_t* __restrict__ xb) {
    size_t i = ((size_t)blockIdx.x * 256 + threadIdx.x) * 8;
    if (i >= ND) return;
    float4 a = *(const float4*)(x + i);
    float4 b = *(const float4*)(x + i + 4);
    uint4 u;
    u.x = (uint32_t)f2bf(a.x) | ((uint32_t)f2bf(a.y) << 16);
    u.y = (uint32_t)f2bf(a.z) | ((uint32_t)f2bf(a.w) << 16);
    u.z = (uint32_t)f2bf(b.x) | ((uint32_t)f2bf(b.y) << 16);
    u.w = (uint32_t)f2bf(b.z) | ((uint32_t)f2bf(b.w) << 16);
    *(uint4*)(xb + i) = u;
}

// ---------------- layer-0 CSR mean-aggregation (shared plane): one wave per node ----------------
__global__ __launch_bounds__(256) void k_agg(const uint16_t* __restrict__ sp, uint16_t* __restrict__ dp,
                                             const int* __restrict__ rp, const int* __restrict__ esrc,
                                             const float* __restrict__ invd) {
    int wave = threadIdx.x >> 6, lane = threadIdx.x & 63;
    int node = blockIdx.x * 4 + wave;
    if (node >= NN) return;
    int beg = rp[node], end = rp[node + 1];
    float s0 = 0, s1 = 0, t0 = 0, t1 = 0;
    int i = beg;
    for (; i + 1 < end; i += 2) {
        int a = esrc[i], b = esrc[i + 1];
        uint32_t va = *(const uint32_t*)(sp + (size_t)a * DD + lane * 2);
        uint32_t vb = *(const uint32_t*)(sp + (size_t)b * DD + lane * 2);
        s0 += bf2f(va & 0xffff); s1 += bf2f(va >> 16);
        t0 += bf2f(vb & 0xffff); t1 += bf2f(vb >> 16);
    }
    if (i < end) {
        uint32_t va = *(const uint32_t*)(sp + (size_t)esrc[i] * DD + lane * 2);
        s0 += bf2f(va & 0xffff); s1 += bf2f(va >> 16);
    }
    float id = invd[node];
    s0 = (s0 + t0) * id; s1 = (s1 + t1) * id;
    *(uint32_t*)(dp + (size_t)node * DD + lane * 2) = (uint32_t)f2bf(s0) | ((uint32_t)f2bf(s1) << 16);
}

// ---------------- layer-1 fused 8-expert aggregation on interleaved [node][e][f] ----------------
// One wave per node; lane owns 32 B (16 bf16) of the 2048 B node-row; one gather of 2 KB per edge
// instead of 8 scattered 256 B gathers. A2 written non-temporally to keep H resident in LLC.
__device__ __forceinline__ void acc_u4(float* a, uint4 u) {
    a[0] += bf2f(u.x & 0xffffu); a[1] += bf2f(u.x >> 16);
    a[2] += bf2f(u.y & 0xffffu); a[3] += bf2f(u.y >> 16);
    a[4] += bf2f(u.z & 0xffffu); a[5] += bf2f(u.z >> 16);
    a[6] += bf2f(u.w & 0xffffu); a[7] += bf2f(u.w >> 16);
}

__global__ __launch_bounds__(256) void k_agg8(const uint16_t* __restrict__ Hi,
                                              uint16_t* __restrict__ A2i,
                                              const int* __restrict__ rp,
                                              const int* __restrict__ esrc,
                                              const float* __restrict__ invd) {
    int wave = threadIdx.x >> 6, lane = threadIdx.x & 63;
    int node = blockIdx.x * 4 + wave;
    if (node >= NN) return;
    int beg = rp[node], end = rp[node + 1];
    float acc[16];
#pragma unroll
    for (int j = 0; j < 16; ++j) acc[j] = 0.f;
    const size_t loff = (size_t)(lane * 16);
    int i = beg;
    for (; i + 1 < end; i += 2) {
        const uint16_t* pa = Hi + (size_t)esrc[i] * 1024 + loff;
        const uint16_t* pb = Hi + (size_t)esrc[i + 1] * 1024 + loff;
        uint4 a0 = *(const uint4*)pa;
        uint4 a1 = *(const uint4*)(pa + 8);
        uint4 b0 = *(const uint4*)pb;
        uint4 b1 = *(const uint4*)(pb + 8);
        acc_u4(acc, a0); acc_u4(acc + 8, a1);
        acc_u4(acc, b0); acc_u4(acc + 8, b1);
    }
    if (i < end) {
        const uint16_t* pa = Hi + (size_t)esrc[i] * 1024 + loff;
        uint4 a0 = *(const uint4*)pa;
        uint4 a1 = *(const uint4*)(pa + 8);
        acc_u4(acc, a0); acc_u4(acc + 8, a1);
    }
    float id = invd[node];
    uint32_t pk[8];
#pragma unroll
    for (int j = 0; j < 8; ++j)
        pk[j] = (uint32_t)f2bf(acc[2 * j] * id) | ((uint32_t)f2bf(acc[2 * j + 1] * id) << 16);
    uint4v o0 = {pk[0], pk[1], pk[2], pk[3]};
    uint4v o1 = {pk[4], pk[5], pk[6], pk[7]};
    uint16_t* dp = A2i + (size_t)node * 1024 + loff;
    __builtin_nontemporal_store(o0, (uint4v*)dp);
    __builtin_nontemporal_store(o1, (uint4v*)(dp + 8));
}

// ---------------- MFMA GEMM: C[rows, 128] = [A1|A2] @ W + b ----------------
// a_rstride: row stride (elems) of A1/A2; a_ezoff: per-expert elem offset into A1/A2.
// out_mode 0: bf16 interleaved H[row*1024 + e*128 + col]   (layer 0)
// out_mode 1: bf16 plane Otmp[e*ND + row*128 + col]        (layer 1)
// out_mode 2: f32 scattered out[row*1024 + col*8 + e]      (fallback)
__global__ __launch_bounds__(256, 2) void k_gemm(
    const float* __restrict__ Wself, const float* __restrict__ Wnbr, const float* __restrict__ bglob,
    int layer,
    const uint16_t* __restrict__ A1, const uint16_t* __restrict__ A2, int a_rstride, int a_ezoff,
    uint16_t* __restrict__ outb, int out_mode, float* __restrict__ outf) {
    __shared__ __align__(16) uint16_t wlds[128 * 256];
    int tid = threadIdx.x;
    int e = blockIdx.z;
    size_t wbase = ((size_t)e * 2 + layer) * (128 * 128);

    // stage W transposed+swizzled into LDS as bf16
    for (int i = tid; i < 128 * 32; i += 256) {
        int n = i & 127, g = i >> 7;               // g = k-group (8 elems)
        uint16_t tmp[8];
#pragma unroll
        for (int j = 0; j < 8; ++j) {
            int k = g * 8 + j;
            float w = (k < 128) ? Wself[wbase + (size_t)k * 128 + n]
                                : Wnbr[wbase + (size_t)(k - 128) * 128 + n];
            tmp[j] = f2bf(w);
        }
        uint4 u;
        u.x = (uint32_t)tmp[0] | ((uint32_t)tmp[1] << 16);
        u.y = (uint32_t)tmp[2] | ((uint32_t)tmp[3] << 16);
        u.z = (uint32_t)tmp[4] | ((uint32_t)tmp[5] << 16);
        u.w = (uint32_t)tmp[6] | ((uint32_t)tmp[7] << 16);
        *(uint4*)&wlds[n * 256 + (((g ^ n) & 31) << 3)] = u;
    }
    __syncthreads();

    const uint16_t* A1p = A1 + (size_t)e * a_ezoff;
    const uint16_t* A2p = A2 + (size_t)e * a_ezoff;

    int wave = tid >> 6, lane = tid & 63;
    int m = lane & 15, quad = lane >> 4;
    int rowBase = blockIdx.x * 256 + wave * 64;

    float4v acc[4][8];
#pragma unroll
    for (int rt = 0; rt < 4; ++rt)
#pragma unroll
        for (int nt = 0; nt < 8; ++nt)
            acc[rt][nt] = (float4v){0.f, 0.f, 0.f, 0.f};

#pragma unroll
    for (int ks = 0; ks < 8; ++ks) {
        int kk = ks * 32 + quad * 8;
        short8 af[4];
#pragma unroll
        for (int rt = 0; rt < 4; ++rt) {
            int row = rowBase + rt * 16 + m;
            row = row < NN ? row : NN - 1;
            const uint16_t* ap = (kk < 128) ? (A1p + (size_t)row * a_rstride + kk)
                                            : (A2p + (size_t)row * a_rstride + (kk - 128));
            af[rt] = *(const short8*)ap;
        }
        int g = kk >> 3;
#pragma unroll
        for (int nt = 0; nt < 8; ++nt) {
            int n = nt * 16 + m;
            short8 bf = *(const short8*)&wlds[n * 256 + (((g ^ n) & 31) << 3)];
#pragma unroll
            for (int rt = 0; rt < 4; ++rt)
                acc[rt][nt] = __builtin_amdgcn_mfma_f32_16x16x32_bf16(af[rt], bf, acc[rt][nt], 0, 0, 0);
        }
    }

    size_t bofs = ((size_t)e * 2 + layer) * 128;
#pragma unroll
    for (int rt = 0; rt < 4; ++rt) {
#pragma unroll
        for (int nt = 0; nt < 8; ++nt) {
            int col = nt * 16 + m;
            float bv = bglob[bofs + col];
#pragma unroll
            for (int r = 0; r < 4; ++r) {
                int row = rowBase + rt * 16 + quad * 4 + r;
                if (row < NN) {
                    float v = acc[rt][nt][r] + bv;
                    if (out_mode == 0) outb[(size_t)row * 1024 + (size_t)e * 128 + col] = f2bf(v);
                    else if (out_mode == 1) outb[(size_t)e * ND + (size_t)row * DD + col] = f2bf(v);
                    else outf[(size_t)row * 1024 + col * 8 + e] = v;
                }
            }
        }
    }
}

// ---------------- BN stats (sum, sumsq per feature) on interleaved H ----------------
__global__ __launch_bounds__(256) void k_stats(const uint16_t* __restrict__ H, float* __restrict__ stats) {
    int e = blockIdx.y;
    const uint16_t* Hp = H + e * 128;
    int f = threadIdx.x & 127, half = threadIdx.x >> 7;
    float s = 0, ss = 0;
    for (int row = blockIdx.x * 2 + half; row < NN; row += gridDim.x * 2) {
        float v = bf2f(Hp[(size_t)row * 1024 + f]);
        s += v; ss += v * v;
    }
    __shared__ float sh[512];
    sh[threadIdx.x] = s; sh[256 + threadIdx.x] = ss;
    __syncthreads();
    if (half == 0) {
        atomicAdd(&stats[e * 256 + f], sh[f] + sh[128 + f]);
        atomicAdd(&stats[e * 256 + 128 + f], sh[256 + f] + sh[256 + 128 + f]);
    }
}

// ---------------- BN coefficients ----------------
__global__ void k_coef(const float* __restrict__ stats, const float* __restrict__ gamma,
                       const float* __restrict__ beta, float* __restrict__ coef) {
    int e = blockIdx.x;
    int f = threadIdx.x;
    float s = stats[e * 256 + f], ss = stats[e * 256 + 128 + f];
    float mean = s / (float)NN;
    float var = ss / (float)NN - mean * mean;
    float sc = gamma[e * 128 + f] * rsqrtf(var + BNEPS);
    coef[e * 256 + f] = sc;
    coef[e * 256 + 128 + f] = beta[e * 128 + f] - mean * sc;
}

// ---------------- affine + ReLU in place on interleaved H ----------------
__global__ __launch_bounds__(256) void k_affine(uint16_t* __restrict__ H, const float* __restrict__ coef) {
    size_t i = ((size_t)blockIdx.x * 256 + threadIdx.x) * 8;
    if (i >= NDE) return;
    int e = (int)((i >> 7) & 7);
    int ff = (int)(i & 127);
    const float* sc = coef + e * 256;
    const float* sf = sc + 128;
    uint4 u = *(const uint4*)(H + i);
    uint32_t w[4] = {u.x, u.y, u.z, u.w};
    uint32_t o[4];
#pragma unroll
    for (int j = 0; j < 4; ++j) {
        float v0 = fmaxf(bf2f(w[j] & 0xffffu) * sc[ff + 2 * j] + sf[ff + 2 * j], 0.f);
        float v1 = fmaxf(bf2f(w[j] >> 16) * sc[ff + 2 * j + 1] + sf[ff + 2 * j + 1], 0.f);
        o[j] = (uint32_t)f2bf(v0) | ((uint32_t)f2bf(v1) << 16);
    }
    uint4 ou = {o[0], o[1], o[2], o[3]};
    *(uint4*)(H + i) = ou;
}

// ---------------- transpose [e][n][f] bf16 -> [n][f][e] f32 ----------------
__global__ __launch_bounds__(256) void k_transpose(const uint16_t* __restrict__ O, float* __restrict__ out) {
    size_t t = (size_t)blockIdx.x * 256 + threadIdx.x;
    if (t >= ND / 2) return;
    size_t idx = t * 2;
    float v0[8], v1[8];
#pragma unroll
    for (int e = 0; e < 8; ++e) {
        uint32_t u = *(const uint32_t*)(O + (size_t)e * ND + idx);
        v0[e] = bf2f(u & 0xffff); v1[e] = bf2f(u >> 16);
    }
    float* op = out + idx * 8;
    float4 a = {v0[0], v0[1], v0[2], v0[3]}, b = {v0[4], v0[5], v0[6], v0[7]};
    float4 c = {v1[0], v1[1], v1[2], v1[3]}, d = {v1[4], v1[5], v1[6], v1[7]};
    *(float4*)(op) = a; *(float4*)(op + 4) = b; *(float4*)(op + 8) = c; *(float4*)(op + 12) = d;
}

extern "C" void kernel_launch(void* const* d_in, const int* in_sizes, int n_in,
                              void* d_out, int out_size, void* d_ws, size_t ws_size,
                              hipStream_t stream) {
    const float* x = (const float*)d_in[0];
    const int* ei = (const int*)d_in[1];
    const float* Wself = (const float*)d_in[2];
    const float* Wnbr = (const float*)d_in[3];
    const float* bias = (const float*)d_in[4];
    const float* gamma = (const float*)d_in[5];
    const float* beta = (const float*)d_in[6];
    float* out = (float*)d_out;
    const int* src = ei;
    const int* dst = ei + NED;

    char* ws = (char*)d_ws;
    size_t off = 0;
    auto alloc = [&](size_t b) { size_t p = off; off += (b + 255) & ~(size_t)255; return p; };
    int* deg = (int*)(ws + alloc((size_t)NN * 4));
    int* rp = (int*)(ws + alloc((size_t)(NN + 1) * 4));
    int* cur = (int*)(ws + alloc((size_t)NN * 4));
    int* esrc = (int*)(ws + alloc((size_t)NED * 4));
    float* invd = (float*)(ws + alloc((size_t)NN * 4));
    int* bsum = (int*)(ws + alloc(98 * 4));
    float* stats = (float*)(ws + alloc(NE * 256 * 4));
    float* coef = (float*)(ws + alloc(NE * 256 * 4));
    uint16_t* xb = (uint16_t*)(ws + alloc(ND * 2));
    uint16_t* agg0 = (uint16_t*)(ws + alloc(ND * 2));

    size_t rem = (ws_size > off) ? ws_size - off : 0;
    size_t plane = ND * 2;  // 25.6 MB
    bool useO = rem >= 24 * plane + 4096;

    uint16_t* Hi = (uint16_t*)(ws + alloc(NE * plane));   // interleaved [node][e][f]
    uint16_t* A2i = (uint16_t*)(ws + alloc(NE * plane));  // interleaved [node][e][f]
    uint16_t* Otmp = useO ? (uint16_t*)(ws + alloc((size_t)NE * plane)) : nullptr;

    hipMemsetAsync(deg, 0, (size_t)NN * 4, stream);
    hipMemsetAsync(stats, 0, NE * 256 * 4, stream);

    k_deg<<<2048, 256, 0, stream>>>(dst, deg);
    k_scan1<<<98, 1024, 0, stream>>>(deg, rp, bsum);
    k_scan2<<<1, 64, 0, stream>>>(bsum);
    k_scan3<<<98, 1024, 0, stream>>>(deg, rp, bsum, cur, invd);
    k_scatter<<<2048, 256, 0, stream>>>(src, dst, cur, esrc);
    k_castx<<<6250, 256, 0, stream>>>(x, xb);

    // layer 0: shared aggregation over x (one plane)
    k_agg<<<25000, 256, 0, stream>>>(xb, agg0, rp, esrc, invd);

    // layer 0 GEMM -> interleaved H
    k_gemm<<<dim3(391, 1, NE), 256, 0, stream>>>(Wself, Wnbr, bias, 0,
                                                 xb, agg0, 128, 0, Hi, 0, nullptr);
    k_stats<<<dim3(500, NE), 256, 0, stream>>>(Hi, stats);
    k_coef<<<NE, 128, 0, stream>>>(stats, gamma, beta, coef);
    k_affine<<<50000, 256, 0, stream>>>(Hi, coef);

    // layer 1: fused 8-expert aggregation on interleaved H
    k_agg8<<<25000, 256, 0, stream>>>(Hi, A2i, rp, esrc, invd);

    if (useO) {
        k_gemm<<<dim3(391, 1, NE), 256, 0, stream>>>(Wself, Wnbr, bias, 1,
                                                     Hi, A2i, 1024, 128, Otmp, 1, nullptr);
        k_transpose<<<25000, 256, 0, stream>>>(Otmp, out);
    } else {
        k_gemm<<<dim3(391, 1, NE), 256, 0, stream>>>(Wself, Wnbr, bias, 1,
                                                     Hi, A2i, 1024, 128, nullptr, 2, out);
    }
}

// Round 3
// 1928.308 us; speedup vs baseline: 1.1321x; 1.0230x over previous
//
#include <hip/hip_runtime.h>
#include <stdint.h>

#define NN 100000
#define NED 1600000
#define DD 128
#define NE 8
#define ND ((size_t)NN * (size_t)DD)     // elems per expert-plane
#define NDE (ND * NE)                    // elems in interleaved [node][e][f]
#define BNEPS 1e-5f

typedef __attribute__((ext_vector_type(8))) short short8;
typedef __attribute__((ext_vector_type(4))) float float4v;
typedef __attribute__((ext_vector_type(4))) unsigned int uint4v;

__device__ __forceinline__ float bf2f(uint32_t h) {
    union { uint32_t u; float f; } c; c.u = h << 16; return c.f;
}
__device__ __forceinline__ uint16_t f2bf(float x) {
    union { float f; uint32_t u; } c; c.f = x;
    uint32_t r = (c.u + 0x7fffu + ((c.u >> 16) & 1u)) >> 16;
    return (uint16_t)r;
}

// ---------------- degree histogram ----------------
__global__ __launch_bounds__(256) void k_deg(const int* __restrict__ dst, int* __restrict__ deg) {
    int i = blockIdx.x * 256 + threadIdx.x;
    int stride = gridDim.x * 256;
    for (; i < NED; i += stride) atomicAdd(&deg[dst[i]], 1);
}

// ---------------- exclusive scan (3 kernels) ----------------
__global__ __launch_bounds__(1024) void k_scan1(const int* __restrict__ deg, int* __restrict__ rp,
                                                int* __restrict__ bsum) {
    __shared__ int sh[1024];
    int t = threadIdx.x;
    int i = blockIdx.x * 1024 + t;
    int v = (i < NN) ? deg[i] : 0;
    sh[t] = v; __syncthreads();
    for (int off = 1; off < 1024; off <<= 1) {
        int add = (t >= off) ? sh[t - off] : 0;
        __syncthreads();
        sh[t] += add;
        __syncthreads();
    }
    if (i < NN) rp[i] = sh[t] - v;            // exclusive
    if (t == 1023) bsum[blockIdx.x] = sh[1023];
}

__global__ void k_scan2(int* bsum) {
    if (threadIdx.x == 0) {
        int acc = 0;
        for (int j = 0; j < 98; ++j) { int t = bsum[j]; bsum[j] = acc; acc += t; }
    }
}

__global__ __launch_bounds__(1024) void k_scan3(const int* __restrict__ deg, int* __restrict__ rp,
                                                const int* __restrict__ bsum, int* __restrict__ cur,
                                                float* __restrict__ invd) {
    int i = blockIdx.x * 1024 + threadIdx.x;
    if (i == 0) rp[NN] = NED;
    if (i < NN) {
        int r = rp[i] + bsum[blockIdx.x];
        rp[i] = r; cur[i] = r;
        invd[i] = 1.0f / fmaxf((float)deg[i], 1.0f);
    }
}

// ---------------- scatter edges into CSR (sorted by dst) ----------------
__global__ __launch_bounds__(256) void k_scatter(const int* __restrict__ src, const int* __restrict__ dst,
                                                 int* __restrict__ cur, int* __restrict__ esrc) {
    int i = blockIdx.x * 256 + threadIdx.x;
    int stride = gridDim.x * 256;
    for (; i < NED; i += stride) {
        int d = dst[i];
        int p = atomicAdd(&cur[d], 1);
        esrc[p] = src[i];
    }
}

// ---------------- cast x (f32 -> bf16) ----------------
__global__ __launch_bounds__(256) void k_castx(const float* __restrict__ x, uint16_t* __restrict__ xb) {
    size_t i = ((size_t)blockIdx.x * 256 + threadIdx.x) * 8;
    if (i >= ND) return;
    float4 a = *(const float4*)(x + i);
    float4 b = *(const float4*)(x + i + 4);
    uint4 u;
    u.x = (uint32_t)f2bf(a.x) | ((uint32_t)f2bf(a.y) << 16);
    u.y = (uint32_t)f2bf(a.z) | ((uint32_t)f2bf(a.w) << 16);
    u.z = (uint32_t)f2bf(b.x) | ((uint32_t)f2bf(b.y) << 16);
    u.w = (uint32_t)f2bf(b.z) | ((uint32_t)f2bf(b.w) << 16);
    *(uint4*)(xb + i) = u;
}

// ---------------- layer-0 CSR mean-aggregation (shared plane): one wave per node ----------------
__global__ __launch_bounds__(256) void k_agg(const uint16_t* __restrict__ sp, uint16_t* __restrict__ dp,
                                             const int* __restrict__ rp, const int* __restrict__ esrc,
                                             const float* __restrict__ invd) {
    int wave = threadIdx.x >> 6, lane = threadIdx.x & 63;
    int node = blockIdx.x * 4 + wave;
    if (node >= NN) return;
    int beg = rp[node], end = rp[node + 1];
    float s0 = 0, s1 = 0, t0 = 0, t1 = 0, u0 = 0, u1 = 0, w0 = 0, w1 = 0;
    int i = beg;
    for (; i + 3 < end; i += 4) {
        int a = esrc[i], b = esrc[i + 1], c = esrc[i + 2], d = esrc[i + 3];
        uint32_t va = *(const uint32_t*)(sp + (size_t)a * DD + lane * 2);
        uint32_t vb = *(const uint32_t*)(sp + (size_t)b * DD + lane * 2);
        uint32_t vc = *(const uint32_t*)(sp + (size_t)c * DD + lane * 2);
        uint32_t vd = *(const uint32_t*)(sp + (size_t)d * DD + lane * 2);
        s0 += bf2f(va & 0xffff); s1 += bf2f(va >> 16);
        t0 += bf2f(vb & 0xffff); t1 += bf2f(vb >> 16);
        u0 += bf2f(vc & 0xffff); u1 += bf2f(vc >> 16);
        w0 += bf2f(vd & 0xffff); w1 += bf2f(vd >> 16);
    }
    for (; i < end; ++i) {
        uint32_t va = *(const uint32_t*)(sp + (size_t)esrc[i] * DD + lane * 2);
        s0 += bf2f(va & 0xffff); s1 += bf2f(va >> 16);
    }
    float id = invd[node];
    s0 = (s0 + t0 + u0 + w0) * id; s1 = (s1 + t1 + u1 + w1) * id;
    *(uint32_t*)(dp + (size_t)node * DD + lane * 2) = (uint32_t)f2bf(s0) | ((uint32_t)f2bf(s1) << 16);
}

// ---------------- layer-1 fused 8-expert aggregation on interleaved [node][e][f] ----------------
// One wave per node; lane owns 32 B (16 bf16) of the 2048 B node-row. 4-edge unroll keeps
// 8 dwordx4 loads in flight per wave (latency-bound gather). A2 written non-temporally.
__device__ __forceinline__ void acc_u4(float* a, uint4 u) {
    a[0] += bf2f(u.x & 0xffffu); a[1] += bf2f(u.x >> 16);
    a[2] += bf2f(u.y & 0xffffu); a[3] += bf2f(u.y >> 16);
    a[4] += bf2f(u.z & 0xffffu); a[5] += bf2f(u.z >> 16);
    a[6] += bf2f(u.w & 0xffffu); a[7] += bf2f(u.w >> 16);
}

__global__ __launch_bounds__(256) void k_agg8(const uint16_t* __restrict__ Hi,
                                              uint16_t* __restrict__ A2i,
                                              const int* __restrict__ rp,
                                              const int* __restrict__ esrc,
                                              const float* __restrict__ invd) {
    int wave = threadIdx.x >> 6, lane = threadIdx.x & 63;
    int node = blockIdx.x * 4 + wave;
    if (node >= NN) return;
    int beg = rp[node], end = rp[node + 1];
    float acc[16];
#pragma unroll
    for (int j = 0; j < 16; ++j) acc[j] = 0.f;
    const size_t loff = (size_t)(lane * 16);
    int i = beg;
    for (; i + 3 < end; i += 4) {
        const uint16_t* p0 = Hi + (size_t)esrc[i] * 1024 + loff;
        const uint16_t* p1 = Hi + (size_t)esrc[i + 1] * 1024 + loff;
        const uint16_t* p2 = Hi + (size_t)esrc[i + 2] * 1024 + loff;
        const uint16_t* p3 = Hi + (size_t)esrc[i + 3] * 1024 + loff;
        uint4 a0 = *(const uint4*)p0;
        uint4 a1 = *(const uint4*)(p0 + 8);
        uint4 b0 = *(const uint4*)p1;
        uint4 b1 = *(const uint4*)(p1 + 8);
        uint4 c0 = *(const uint4*)p2;
        uint4 c1 = *(const uint4*)(p2 + 8);
        uint4 d0 = *(const uint4*)p3;
        uint4 d1 = *(const uint4*)(p3 + 8);
        acc_u4(acc, a0); acc_u4(acc + 8, a1);
        acc_u4(acc, b0); acc_u4(acc + 8, b1);
        acc_u4(acc, c0); acc_u4(acc + 8, c1);
        acc_u4(acc, d0); acc_u4(acc + 8, d1);
    }
    for (; i < end; ++i) {
        const uint16_t* pa = Hi + (size_t)esrc[i] * 1024 + loff;
        uint4 a0 = *(const uint4*)pa;
        uint4 a1 = *(const uint4*)(pa + 8);
        acc_u4(acc, a0); acc_u4(acc + 8, a1);
    }
    float id = invd[node];
    uint32_t pk[8];
#pragma unroll
    for (int j = 0; j < 8; ++j)
        pk[j] = (uint32_t)f2bf(acc[2 * j] * id) | ((uint32_t)f2bf(acc[2 * j + 1] * id) << 16);
    uint4v o0 = {pk[0], pk[1], pk[2], pk[3]};
    uint4v o1 = {pk[4], pk[5], pk[6], pk[7]};
    uint16_t* dp = A2i + (size_t)node * 1024 + loff;
    __builtin_nontemporal_store(o0, (uint4v*)dp);
    __builtin_nontemporal_store(o1, (uint4v*)(dp + 8));
}

// ---------------- MFMA GEMM: C[rows, 128] = [A1|A2] @ W + b ----------------
// a_rstride: row stride (elems) of A1/A2; a_ezoff: per-expert elem offset into A1/A2.
// out_mode 0: bf16 interleaved H[row*1024 + e*128 + col]   (layer 0)
// out_mode 1: bf16 plane Otmp[e*ND + row*128 + col]        (layer 1)
// out_mode 2: f32 scattered out[row*1024 + col*8 + e]      (fallback)
// do_stats: accumulate per-column sum/sumsq of f32 outputs into stats[e*256 + {f,128+f}]
__global__ __launch_bounds__(256, 2) void k_gemm(
    const float* __restrict__ Wself, const float* __restrict__ Wnbr, const float* __restrict__ bglob,
    int layer,
    const uint16_t* __restrict__ A1, const uint16_t* __restrict__ A2, int a_rstride, int a_ezoff,
    uint16_t* __restrict__ outb, int out_mode, float* __restrict__ outf,
    int do_stats, float* __restrict__ stats) {
    __shared__ __align__(16) uint16_t wlds[128 * 256];
    __shared__ float ssum[128];
    __shared__ float ssq[128];
    int tid = threadIdx.x;
    int e = blockIdx.z;
    size_t wbase = ((size_t)e * 2 + layer) * (128 * 128);

    // stage W transposed+swizzled into LDS as bf16
    for (int i = tid; i < 128 * 32; i += 256) {
        int n = i & 127, g = i >> 7;               // g = k-group (8 elems)
        uint16_t tmp[8];
#pragma unroll
        for (int j = 0; j < 8; ++j) {
            int k = g * 8 + j;
            float w = (k < 128) ? Wself[wbase + (size_t)k * 128 + n]
                                : Wnbr[wbase + (size_t)(k - 128) * 128 + n];
            tmp[j] = f2bf(w);
        }
        uint4 u;
        u.x = (uint32_t)tmp[0] | ((uint32_t)tmp[1] << 16);
        u.y = (uint32_t)tmp[2] | ((uint32_t)tmp[3] << 16);
        u.z = (uint32_t)tmp[4] | ((uint32_t)tmp[5] << 16);
        u.w = (uint32_t)tmp[6] | ((uint32_t)tmp[7] << 16);
        *(uint4*)&wlds[n * 256 + (((g ^ n) & 31) << 3)] = u;
    }
    if (tid < 128) { ssum[tid] = 0.f; ssq[tid] = 0.f; }
    __syncthreads();

    const uint16_t* A1p = A1 + (size_t)e * a_ezoff;
    const uint16_t* A2p = A2 + (size_t)e * a_ezoff;

    int wave = tid >> 6, lane = tid & 63;
    int m = lane & 15, quad = lane >> 4;
    int rowBase = blockIdx.x * 256 + wave * 64;

    float4v acc[4][8];
#pragma unroll
    for (int rt = 0; rt < 4; ++rt)
#pragma unroll
        for (int nt = 0; nt < 8; ++nt)
            acc[rt][nt] = (float4v){0.f, 0.f, 0.f, 0.f};

#pragma unroll
    for (int ks = 0; ks < 8; ++ks) {
        int kk = ks * 32 + quad * 8;
        short8 af[4];
#pragma unroll
        for (int rt = 0; rt < 4; ++rt) {
            int row = rowBase + rt * 16 + m;
            row = row < NN ? row : NN - 1;
            const uint16_t* ap = (kk < 128) ? (A1p + (size_t)row * a_rstride + kk)
                                            : (A2p + (size_t)row * a_rstride + (kk - 128));
            af[rt] = *(const short8*)ap;
        }
        int g = kk >> 3;
#pragma unroll
        for (int nt = 0; nt < 8; ++nt) {
            int n = nt * 16 + m;
            short8 bf = *(const short8*)&wlds[n * 256 + (((g ^ n) & 31) << 3)];
#pragma unroll
            for (int rt = 0; rt < 4; ++rt)
                acc[rt][nt] = __builtin_amdgcn_mfma_f32_16x16x32_bf16(af[rt], bf, acc[rt][nt], 0, 0, 0);
        }
    }

    float csum[8], csq[8];
#pragma unroll
    for (int nt = 0; nt < 8; ++nt) { csum[nt] = 0.f; csq[nt] = 0.f; }

    size_t bofs = ((size_t)e * 2 + layer) * 128;
#pragma unroll
    for (int rt = 0; rt < 4; ++rt) {
#pragma unroll
        for (int nt = 0; nt < 8; ++nt) {
            int col = nt * 16 + m;
            float bv = bglob[bofs + col];
#pragma unroll
            for (int r = 0; r < 4; ++r) {
                int row = rowBase + rt * 16 + quad * 4 + r;
                if (row < NN) {
                    float v = acc[rt][nt][r] + bv;
                    if (out_mode == 0) outb[(size_t)row * 1024 + (size_t)e * 128 + col] = f2bf(v);
                    else if (out_mode == 1) outb[(size_t)e * ND + (size_t)row * DD + col] = f2bf(v);
                    else outf[(size_t)row * 1024 + col * 8 + e] = v;
                    if (do_stats) { csum[nt] += v; csq[nt] += v * v; }
                }
            }
        }
    }

    if (do_stats) {
        // cross-lane: lanes {m, m+16, m+32, m+48} hold the same column
#pragma unroll
        for (int nt = 0; nt < 8; ++nt) {
            float s = csum[nt], q = csq[nt];
            s += __shfl_xor(s, 16); q += __shfl_xor(q, 16);
            s += __shfl_xor(s, 32); q += __shfl_xor(q, 32);
            if (quad == 0) {
                atomicAdd(&ssum[nt * 16 + m], s);
                atomicAdd(&ssq[nt * 16 + m], q);
            }
        }
        __syncthreads();
        if (tid < 128) {
            atomicAdd(&stats[e * 256 + tid], ssum[tid]);
            atomicAdd(&stats[e * 256 + 128 + tid], ssq[tid]);
        }
    }
}

// ---------------- BN coefficients ----------------
__global__ void k_coef(const float* __restrict__ stats, const float* __restrict__ gamma,
                       const float* __restrict__ beta, float* __restrict__ coef) {
    int e = blockIdx.x;
    int f = threadIdx.x;
    float s = stats[e * 256 + f], ss = stats[e * 256 + 128 + f];
    float mean = s / (float)NN;
    float var = ss / (float)NN - mean * mean;
    float sc = gamma[e * 128 + f] * rsqrtf(var + BNEPS);
    coef[e * 256 + f] = sc;
    coef[e * 256 + 128 + f] = beta[e * 128 + f] - mean * sc;
}

// ---------------- affine + ReLU in place on interleaved H ----------------
__global__ __launch_bounds__(256) void k_affine(uint16_t* __restrict__ H, const float* __restrict__ coef) {
    size_t i = ((size_t)blockIdx.x * 256 + threadIdx.x) * 8;
    if (i >= NDE) return;
    int e = (int)((i >> 7) & 7);
    int ff = (int)(i & 127);
    const float* sc = coef + e * 256;
    const float* sf = sc + 128;
    uint4 u = *(const uint4*)(H + i);
    uint32_t w[4] = {u.x, u.y, u.z, u.w};
    uint32_t o[4];
#pragma unroll
    for (int j = 0; j < 4; ++j) {
        float v0 = fmaxf(bf2f(w[j] & 0xffffu) * sc[ff + 2 * j] + sf[ff + 2 * j], 0.f);
        float v1 = fmaxf(bf2f(w[j] >> 16) * sc[ff + 2 * j + 1] + sf[ff + 2 * j + 1], 0.f);
        o[j] = (uint32_t)f2bf(v0) | ((uint32_t)f2bf(v1) << 16);
    }
    uint4 ou = {o[0], o[1], o[2], o[3]};
    *(uint4*)(H + i) = ou;
}

// ---------------- transpose [e][n][f] bf16 -> [n][f][e] f32 ----------------
__global__ __launch_bounds__(256) void k_transpose(const uint16_t* __restrict__ O, float* __restrict__ out) {
    size_t t = (size_t)blockIdx.x * 256 + threadIdx.x;
    if (t >= ND / 2) return;
    size_t idx = t * 2;
    float v0[8], v1[8];
#pragma unroll
    for (int e = 0; e < 8; ++e) {
        uint32_t u = *(const uint32_t*)(O + (size_t)e * ND + idx);
        v0[e] = bf2f(u & 0xffff); v1[e] = bf2f(u >> 16);
    }
    float* op = out + idx * 8;
    float4 a = {v0[0], v0[1], v0[2], v0[3]}, b = {v0[4], v0[5], v0[6], v0[7]};
    float4 c = {v1[0], v1[1], v1[2], v1[3]}, d = {v1[4], v1[5], v1[6], v1[7]};
    *(float4*)(op) = a; *(float4*)(op + 4) = b; *(float4*)(op + 8) = c; *(float4*)(op + 12) = d;
}

extern "C" void kernel_launch(void* const* d_in, const int* in_sizes, int n_in,
                              void* d_out, int out_size, void* d_ws, size_t ws_size,
                              hipStream_t stream) {
    const float* x = (const float*)d_in[0];
    const int* ei = (const int*)d_in[1];
    const float* Wself = (const float*)d_in[2];
    const float* Wnbr = (const float*)d_in[3];
    const float* bias = (const float*)d_in[4];
    const float* gamma = (const float*)d_in[5];
    const float* beta = (const float*)d_in[6];
    float* out = (float*)d_out;
    const int* src = ei;
    const int* dst = ei + NED;

    char* ws = (char*)d_ws;
    size_t off = 0;
    auto alloc = [&](size_t b) { size_t p = off; off += (b + 255) & ~(size_t)255; return p; };
    int* deg = (int*)(ws + alloc((size_t)NN * 4));
    int* rp = (int*)(ws + alloc((size_t)(NN + 1) * 4));
    int* cur = (int*)(ws + alloc((size_t)NN * 4));
    int* esrc = (int*)(ws + alloc((size_t)NED * 4));
    float* invd = (float*)(ws + alloc((size_t)NN * 4));
    int* bsum = (int*)(ws + alloc(98 * 4));
    float* stats = (float*)(ws + alloc(NE * 256 * 4));
    float* coef = (float*)(ws + alloc(NE * 256 * 4));
    uint16_t* xb = (uint16_t*)(ws + alloc(ND * 2));
    uint16_t* agg0 = (uint16_t*)(ws + alloc(ND * 2));

    size_t rem = (ws_size > off) ? ws_size - off : 0;
    size_t plane = ND * 2;  // 25.6 MB
    bool useO = rem >= 24 * plane + 4096;

    uint16_t* Hi = (uint16_t*)(ws + alloc(NE * plane));   // interleaved [node][e][f]
    uint16_t* A2i = (uint16_t*)(ws + alloc(NE * plane));  // interleaved [node][e][f]
    uint16_t* Otmp = useO ? (uint16_t*)(ws + alloc((size_t)NE * plane)) : nullptr;

    hipMemsetAsync(deg, 0, (size_t)NN * 4, stream);
    hipMemsetAsync(stats, 0, NE * 256 * 4, stream);

    k_deg<<<2048, 256, 0, stream>>>(dst, deg);
    k_scan1<<<98, 1024, 0, stream>>>(deg, rp, bsum);
    k_scan2<<<1, 64, 0, stream>>>(bsum);
    k_scan3<<<98, 1024, 0, stream>>>(deg, rp, bsum, cur, invd);
    k_scatter<<<2048, 256, 0, stream>>>(src, dst, cur, esrc);
    k_castx<<<6250, 256, 0, stream>>>(x, xb);

    // layer 0: shared aggregation over x (one plane)
    k_agg<<<25000, 256, 0, stream>>>(xb, agg0, rp, esrc, invd);

    // layer 0 GEMM -> interleaved H, with fused BN-stats epilogue
    k_gemm<<<dim3(391, 1, NE), 256, 0, stream>>>(Wself, Wnbr, bias, 0,
                                                 xb, agg0, 128, 0, Hi, 0, nullptr, 1, stats);
    k_coef<<<NE, 128, 0, stream>>>(stats, gamma, beta, coef);
    k_affine<<<50000, 256, 0, stream>>>(Hi, coef);

    // layer 1: fused 8-expert aggregation on interleaved H
    k_agg8<<<25000, 256, 0, stream>>>(Hi, A2i, rp, esrc, invd);

    if (useO) {
        k_gemm<<<dim3(391, 1, NE), 256, 0, stream>>>(Wself, Wnbr, bias, 1,
                                                     Hi, A2i, 1024, 128, Otmp, 1, nullptr, 0, nullptr);
        k_transpose<<<25000, 256, 0, stream>>>(Otmp, out);
    } else {
        k_gemm<<<dim3(391, 1, NE), 256, 0, stream>>>(Wself, Wnbr, bias, 1,
                                                     Hi, A2i, 1024, 128, nullptr, 2, out, 0, nullptr);
    }
}